// Round 6
// baseline (381.803 us; speedup 1.0000x reference)
//
#include <hip/hip_runtime.h>

#define DM   1024
#define DFF  4096
#define NH   16
#define HD   64
#define TT   2048
#define BT   4096   // B*T

typedef unsigned short u16;
typedef unsigned int   u32;
typedef __attribute__((ext_vector_type(8))) short s16x8;
typedef __attribute__((ext_vector_type(4))) float f32x4;

__device__ __forceinline__ u16 f2bf(float f) {
  u32 u = __builtin_bit_cast(u32, f);
  u += 0x7fffu + ((u >> 16) & 1u);
  return (u16)(u >> 16);
}

// async global->LDS, 16B per lane. HW semantics: dest = wave-uniform base + lane*16.
__device__ __forceinline__ void gl2lds16(const void* g, void* l) {
  __builtin_amdgcn_global_load_lds((__attribute__((address_space(1))) void*)(g),
                                   (__attribute__((address_space(3))) void*)(l),
                                   16, 0, 0);
}

// ------- RMSNorm: x fp32 [BT][DM] -> xn bf16; also d_out = x (residual base) -------
__global__ __launch_bounds__(256) void rmsnorm_k(const float* __restrict__ x,
                                                 const float* __restrict__ w,
                                                 u16* __restrict__ xn,
                                                 float* __restrict__ dout) {
  const int row = blockIdx.x;
  const int t = threadIdx.x;
  const float4 v = ((const float4*)(x + (size_t)row * DM))[t];
  ((float4*)(dout + (size_t)row * DM))[t] = v;       // residual base for atomics
  float ss = v.x*v.x + v.y*v.y + v.z*v.z + v.w*v.w;
  #pragma unroll
  for (int off = 32; off; off >>= 1) ss += __shfl_xor(ss, off, 64);
  __shared__ float red[4];
  if ((t & 63) == 0) red[t >> 6] = ss;
  __syncthreads();
  const float tot = red[0] + red[1] + red[2] + red[3];
  const float r = __builtin_amdgcn_rsqf(tot * (1.0f / DM) + 1.1920929e-7f);
  const float4 wv = ((const float4*)w)[t];
  u16* o = xn + (size_t)row * DM + t * 4;
  o[0] = f2bf(v.x * r * wv.x);
  o[1] = f2bf(v.y * r * wv.y);
  o[2] = f2bf(v.z * r * wv.z);
  o[3] = f2bf(v.w * r * wv.w);
}

// ------------- weight transpose+cvt: W fp32 [K][N] -> Wt bf16 [N][K] -------------
__global__ __launch_bounds__(256) void wtrans_k(const float* __restrict__ W,
                                                u16* __restrict__ Wt,
                                                int K, int N) {
  __shared__ float tile[32][33];
  const int n0 = blockIdx.x * 32, k0 = blockIdx.y * 32;
  const int tx = threadIdx.x, ty = threadIdx.y;  // (32,8)
  #pragma unroll
  for (int i = 0; i < 4; ++i)
    tile[ty + i*8][tx] = W[(size_t)(k0 + ty + i*8) * N + n0 + tx];
  __syncthreads();
  #pragma unroll
  for (int i = 0; i < 4; ++i)
    Wt[(size_t)(n0 + ty + i*8) * K + k0 + tx] = f2bf(tile[tx][ty + i*8]);
}

// ---- fused QKV+FFN1 GEMM: A=xn [4096][1024], Bt=wqkv1_t [7168][1024] ----
// col<1024 (Q): *scale -> qkb; <2048 (K): qkb; <3072 (V): transposed vtg;
// >=3072: silu -> ff1 [4096][4096]
__global__ __launch_bounds__(256, 2) void gemm_fused(const u16* __restrict__ A,
                                                     const u16* __restrict__ Bt,
                                                     u16* __restrict__ qkb,
                                                     u16* __restrict__ vtg,
                                                     u16* __restrict__ ff1) {
  const int K = 1024;
  __shared__ u16 sA[128 * 32];
  __shared__ u16 sB[128 * 32];
  const int t = threadIdx.x;
  const int lane = t & 63, wave = t >> 6;
  const int quad = lane >> 4, l4 = lane & 15;
  const int wy = wave >> 1, wx = wave & 1;
  const size_t mBase = (size_t)blockIdx.y * 128;
  const size_t nBase = (size_t)blockIdx.x * 128;
  const int r  = t >> 2;
  const int c8 = (t & 3) * 8;
  const u16* Ag0 = A + (mBase + r) * K + c8;
  const u16* Ag1 = Ag0 + (size_t)64 * K;
  const u16* Bg0 = Bt + (nBase + r) * K + c8;
  const u16* Bg1 = Bg0 + (size_t)64 * K;
  char* sAb = (char*)sA + (wave << 10);
  char* sBb = (char*)sB + (wave << 10);

  f32x4 acc[4][4];
  #pragma unroll
  for (int i = 0; i < 4; ++i)
    #pragma unroll
    for (int j = 0; j < 4; ++j)
      acc[i][j] = (f32x4)0.0f;

  for (int k0 = 0; k0 < K; k0 += 32) {
    __syncthreads();
    gl2lds16(Ag0 + k0, sAb);
    gl2lds16(Ag1 + k0, sAb + 4096);
    gl2lds16(Bg0 + k0, sBb);
    gl2lds16(Bg1 + k0, sBb + 4096);
    __syncthreads();
    s16x8 af[4], bfr[4];
    #pragma unroll
    for (int i = 0; i < 4; ++i)
      af[i] = *(const s16x8*)&sA[(wy*64 + i*16 + l4) * 32 + quad*8];
    #pragma unroll
    for (int j = 0; j < 4; ++j)
      bfr[j] = *(const s16x8*)&sB[(wx*64 + j*16 + l4) * 32 + quad*8];
    #pragma unroll
    for (int i = 0; i < 4; ++i)
      #pragma unroll
      for (int j = 0; j < 4; ++j)
        acc[i][j] = __builtin_amdgcn_mfma_f32_16x16x32_bf16(af[i], bfr[j], acc[i][j], 0, 0, 0);
  }

  // block-uniform region select (boundaries 1024/2048/3072 are 128-aligned)
  #pragma unroll
  for (int i = 0; i < 4; ++i) {
    const size_t row0 = mBase + wy*64 + i*16 + quad*4;
    #pragma unroll
    for (int j = 0; j < 4; ++j) {
      const int col = (int)nBase + wx*64 + j*16 + l4;
      if (nBase < 1024) {               // Q: fold (1/sqrt(64))*log2(e)
        #pragma unroll
        for (int rg = 0; rg < 4; ++rg)
          qkb[(row0 + rg) * 2048 + col] = f2bf(acc[i][j][rg] * 0.18033688011f);
      } else if (nBase < 2048) {        // K
        #pragma unroll
        for (int rg = 0; rg < 4; ++rg)
          qkb[(row0 + rg) * 2048 + col] = f2bf(acc[i][j][rg]);
      } else if (nBase < 3072) {        // V: transposed, 4 tokens packed
        const int cv = col - 2048, hh = cv >> 6, dd = cv & 63;
        const int bb = (int)(row0 >> 11), t0 = (int)(row0 & 2047);
        ushort4 pk;
        pk.x = f2bf(acc[i][j][0]); pk.y = f2bf(acc[i][j][1]);
        pk.z = f2bf(acc[i][j][2]); pk.w = f2bf(acc[i][j][3]);
        *(ushort4*)(vtg + ((size_t)((bb*16 + hh)*64 + dd)) * 2048 + t0) = pk;
      } else {                          // FFN1: silu
        #pragma unroll
        for (int rg = 0; rg < 4; ++rg) {
          float v = acc[i][j][rg];
          v = v / (1.0f + __expf(-v));
          ff1[(row0 + rg) * (size_t)DFF + (col - 3072)] = f2bf(v);
        }
      }
    }
  }
}

// ---- split-K GEMM with fp32 atomic accumulate into out [M][1024] ----
// grid (8, M/128, z); kBase = z*KS. out pre-initialized with residual base.
__global__ __launch_bounds__(256, 2) void gemm_atomic(const u16* __restrict__ A,
                                                      const u16* __restrict__ Bt,
                                                      float* __restrict__ out,
                                                      int K, int KS) {
  const int N = 1024;
  __shared__ u16 sA[128 * 32];
  __shared__ u16 sB[128 * 32];
  const int t = threadIdx.x;
  const int lane = t & 63, wave = t >> 6;
  const int quad = lane >> 4, l4 = lane & 15;
  const int wy = wave >> 1, wx = wave & 1;
  const size_t mBase = (size_t)blockIdx.y * 128;
  const size_t nBase = (size_t)blockIdx.x * 128;
  const int kBase = blockIdx.z * KS;
  const int r  = t >> 2;
  const int c8 = (t & 3) * 8;
  const u16* Ag0 = A + (mBase + r) * K + kBase + c8;
  const u16* Ag1 = Ag0 + (size_t)64 * K;
  const u16* Bg0 = Bt + (nBase + r) * K + kBase + c8;
  const u16* Bg1 = Bg0 + (size_t)64 * K;
  char* sAb = (char*)sA + (wave << 10);
  char* sBb = (char*)sB + (wave << 10);

  f32x4 acc[4][4];
  #pragma unroll
  for (int i = 0; i < 4; ++i)
    #pragma unroll
    for (int j = 0; j < 4; ++j)
      acc[i][j] = (f32x4)0.0f;

  for (int k0 = 0; k0 < KS; k0 += 32) {
    __syncthreads();
    gl2lds16(Ag0 + k0, sAb);
    gl2lds16(Ag1 + k0, sAb + 4096);
    gl2lds16(Bg0 + k0, sBb);
    gl2lds16(Bg1 + k0, sBb + 4096);
    __syncthreads();
    s16x8 af[4], bfr[4];
    #pragma unroll
    for (int i = 0; i < 4; ++i)
      af[i] = *(const s16x8*)&sA[(wy*64 + i*16 + l4) * 32 + quad*8];
    #pragma unroll
    for (int j = 0; j < 4; ++j)
      bfr[j] = *(const s16x8*)&sB[(wx*64 + j*16 + l4) * 32 + quad*8];
    #pragma unroll
    for (int i = 0; i < 4; ++i)
      #pragma unroll
      for (int j = 0; j < 4; ++j)
        acc[i][j] = __builtin_amdgcn_mfma_f32_16x16x32_bf16(af[i], bfr[j], acc[i][j], 0, 0, 0);
  }

  #pragma unroll
  for (int i = 0; i < 4; ++i) {
    const size_t row0 = mBase + wy*64 + i*16 + quad*4;
    #pragma unroll
    for (int j = 0; j < 4; ++j) {
      const int col = (int)nBase + wx*64 + j*16 + l4;
      #pragma unroll
      for (int rg = 0; rg < 4; ++rg)
        unsafeAtomicAdd(&out[(row0 + rg) * (size_t)N + col], acc[i][j][rg]);
    }
  }
}

// ------- causal flash attention, fixed-max, in-block split-K=2 over waves -------
// (unchanged from R5 — no min-waves clamp; (128,4) caused scratch spills)
__global__ __launch_bounds__(128) void attn_k(const u16* __restrict__ qk,
                                              const u16* __restrict__ vtg,
                                              u16* __restrict__ ao) {
  const int bh = blockIdx.x, b = bh >> 4, h = bh & 15;
  const int qt = 63 - blockIdx.y;
  const int qw = qt * 32;
  const int wave = threadIdx.x >> 6, lane = threadIdx.x & 63;
  const int quad = lane >> 4, l4 = lane & 15;
  const u16* Qp = qk + (size_t)b * TT * 2048 + h * HD;
  const u16* Kp = Qp + 1024;
  const u16* Vp = vtg + (size_t)bh * 64 * 2048;

  __shared__ u16 Pb[2][32][72];
  __shared__ float Ob[32][68];
  __shared__ float Lb[32];

  s16x8 qf[2][2];
  #pragma unroll
  for (int mi = 0; mi < 2; ++mi)
    #pragma unroll
    for (int kf = 0; kf < 2; ++kf)
      qf[mi][kf] = *(const s16x8*)(Qp + (size_t)(qw + mi*16 + l4) * 2048 + kf*32 + quad*8);

  const s16x8 ones = {0x3F80,0x3F80,0x3F80,0x3F80,0x3F80,0x3F80,0x3F80,0x3F80};

  f32x4 o[2][4];
  f32x4 lacc[2];
  #pragma unroll
  for (int mi = 0; mi < 2; ++mi) {
    lacc[mi] = (f32x4)0.0f;
    #pragma unroll
    for (int ni = 0; ni < 4; ++ni) o[mi][ni] = (f32x4)0.0f;
  }

  const int n   = (qt + 2) >> 1;
  const int n0  = (n + 1) >> 1;
  const int kt0 = wave ? n0 : 0;
  const int kt1 = wave ? n : n0;

  for (int kt = kt0; kt < kt1; ++kt) {
    const int k0 = kt * 64;

    f32x4 st[4][2];
    #pragma unroll
    for (int nj = 0; nj < 4; ++nj) {
      const u16* kr = Kp + (size_t)(k0 + nj*16 + l4) * 2048 + quad*8;
      const s16x8 kf0 = *(const s16x8*)kr;
      const s16x8 kf1 = *(const s16x8*)(kr + 32);
      #pragma unroll
      for (int mi = 0; mi < 2; ++mi) {
        f32x4 a = (f32x4)0.0f;
        a = __builtin_amdgcn_mfma_f32_16x16x32_bf16(kf0, qf[mi][0], a, 0, 0, 0);
        a = __builtin_amdgcn_mfma_f32_16x16x32_bf16(kf1, qf[mi][1], a, 0, 0, 0);
        st[nj][mi] = a;
      }
    }

    s16x8 vb[2][4];
    #pragma unroll
    for (int kf2 = 0; kf2 < 2; ++kf2)
      #pragma unroll
      for (int ni = 0; ni < 4; ++ni)
        vb[kf2][ni] = *(const s16x8*)(Vp + (size_t)(ni*16 + l4) * 2048 + k0 + kf2*32 + quad*8);

    if (k0 + 63 > qw) {
      #pragma unroll
      for (int nj = 0; nj < 4; ++nj)
        #pragma unroll
        for (int mi = 0; mi < 2; ++mi)
          #pragma unroll
          for (int rg = 0; rg < 4; ++rg) {
            const int key = k0 + nj*16 + quad*4 + rg;
            const int q   = qw + mi*16 + l4;
            if (key > q) st[nj][mi][rg] = -1e30f;
          }
    }

    #pragma unroll
    for (int nj = 0; nj < 4; ++nj)
      #pragma unroll
      for (int mi = 0; mi < 2; ++mi) {
        float p0 = __builtin_amdgcn_exp2f(st[nj][mi][0]);
        float p1 = __builtin_amdgcn_exp2f(st[nj][mi][1]);
        float p2 = __builtin_amdgcn_exp2f(st[nj][mi][2]);
        float p3 = __builtin_amdgcn_exp2f(st[nj][mi][3]);
        uint2 w;
        w.x = __builtin_amdgcn_perm(__builtin_bit_cast(u32, p1),
                                    __builtin_bit_cast(u32, p0), 0x07060302u);
        w.y = __builtin_amdgcn_perm(__builtin_bit_cast(u32, p3),
                                    __builtin_bit_cast(u32, p2), 0x07060302u);
        *(uint2*)&Pb[wave][mi*16 + l4][nj*16 + quad*4] = w;
      }

    #pragma unroll
    for (int kf2 = 0; kf2 < 2; ++kf2) {
      s16x8 pa[2];
      #pragma unroll
      for (int mi = 0; mi < 2; ++mi)
        pa[mi] = *(const s16x8*)&Pb[wave][mi*16 + l4][kf2*32 + quad*8];
      #pragma unroll
      for (int mi = 0; mi < 2; ++mi) {
        lacc[mi] = __builtin_amdgcn_mfma_f32_16x16x32_bf16(pa[mi], ones, lacc[mi], 0, 0, 0);
        #pragma unroll
        for (int ni = 0; ni < 4; ++ni)
          o[mi][ni] = __builtin_amdgcn_mfma_f32_16x16x32_bf16(pa[mi], vb[kf2][ni], o[mi][ni], 0, 0, 0);
      }
    }
  }

  if (wave == 1) {
    #pragma unroll
    for (int mi = 0; mi < 2; ++mi)
      #pragma unroll
      for (int rg = 0; rg < 4; ++rg) {
        const int row = mi*16 + quad*4 + rg;
        #pragma unroll
        for (int ni = 0; ni < 4; ++ni) Ob[row][ni*16 + l4] = o[mi][ni][rg];
        if (l4 == 0) Lb[row] = lacc[mi][rg];
      }
  }
  __syncthreads();
  if (wave == 0) {
    #pragma unroll
    for (int mi = 0; mi < 2; ++mi)
      #pragma unroll
      for (int rg = 0; rg < 4; ++rg) {
        const int row = mi*16 + quad*4 + rg;
        const float inv = 1.0f / (lacc[mi][rg] + Lb[row]);
        #pragma unroll
        for (int ni = 0; ni < 4; ++ni)
          Pb[0][row][ni*16 + l4] = f2bf((o[mi][ni][rg] + Ob[row][ni*16 + l4]) * inv);
      }
    #pragma unroll
    for (int it = 0; it < 4; ++it) {
      const int row = it*8 + (lane >> 3);
      const int c0  = (lane & 7) * 8;
      const s16x8 pk = *(const s16x8*)&Pb[0][row][c0];
      *(s16x8*)(ao + ((size_t)b * TT + qw + row) * DM + h*HD + c0) = pk;
    }
  }
}

extern "C" void kernel_launch(void* const* d_in, const int* in_sizes, int n_in,
                              void* d_out, int out_size, void* d_ws, size_t ws_size,
                              hipStream_t stream) {
  (void)in_sizes; (void)n_in; (void)out_size; (void)ws_size;
  const float* x  = (const float*)d_in[0];
  const float* nw = (const float*)d_in[1];
  const float* Wq = (const float*)d_in[2];
  const float* Wk = (const float*)d_in[3];
  const float* Wv = (const float*)d_in[4];
  const float* Wo = (const float*)d_in[5];
  const float* W1 = (const float*)d_in[6];
  const float* W2 = (const float*)d_in[7];

  char* ws = (char*)d_ws;
  u16*   xn      = (u16*)(ws);                          //  8 MB  [4096][1024]
  u16*   wqkv1_t = (u16*)(ws + ((size_t)8  << 20));     // 14 MB  [7168][1024] Wq|Wk|Wv|W1 ^T
  u16*   wo_t    = (u16*)(ws + ((size_t)22 << 20));     //  2 MB  [1024][1024]
  u16*   w2_t    = (u16*)(ws + ((size_t)24 << 20));     //  8 MB  [1024][4096]
  u16*   qkb     = (u16*)(ws + ((size_t)32 << 20));     // 16 MB  [4096][2048] (q|k)
  u16*   vtg     = (u16*)(ws + ((size_t)48 << 20));     //  8 MB  [32][64][2048] V^T
  u16*   attn_o  = (u16*)(ws + ((size_t)56 << 20));     //  8 MB  [4096][1024]
  u16*   ff1     = (u16*)(ws + ((size_t)64 << 20));     // 32 MB  [4096][4096]
  float* dout    = (float*)d_out;                       // 16 MB  [4096][1024] fp32

  rmsnorm_k<<<BT, 256, 0, stream>>>(x, nw, xn, dout);
  const dim3 tb(32, 8);
  wtrans_k<<<dim3(32, 32),  tb, 0, stream>>>(Wq, wqkv1_t,                      1024, 1024);
  wtrans_k<<<dim3(32, 32),  tb, 0, stream>>>(Wk, wqkv1_t + (size_t)1024*1024,  1024, 1024);
  wtrans_k<<<dim3(32, 32),  tb, 0, stream>>>(Wv, wqkv1_t + (size_t)2048*1024,  1024, 1024);
  wtrans_k<<<dim3(128, 32), tb, 0, stream>>>(W1, wqkv1_t + (size_t)3072*1024,  1024, 4096);
  wtrans_k<<<dim3(32, 32),  tb, 0, stream>>>(Wo, wo_t,                         1024, 1024);
  wtrans_k<<<dim3(32, 128), tb, 0, stream>>>(W2, w2_t,                         4096, 1024);

  gemm_fused<<<dim3(56, 32), 256, 0, stream>>>(xn, wqkv1_t, qkb, vtg, ff1);
  gemm_atomic<<<dim3(8, 32, 2), 256, 0, stream>>>(ff1, w2_t, dout, 4096, 2048);  // FFN2
  attn_k<<<dim3(32, 64), 128, 0, stream>>>(qkb, vtg, attn_o);
  gemm_atomic<<<dim3(8, 32, 2), 256, 0, stream>>>(attn_o, wo_t, dout, 1024, 512); // Wo proj
}

// Round 7
// 377.246 us; speedup vs baseline: 1.0121x; 1.0121x over previous
//
#include <hip/hip_runtime.h>

#define DM   1024
#define DFF  4096
#define NH   16
#define HD   64
#define TT   2048
#define BT   4096   // B*T
#define KC   5120   // concat-K: 1024 (attn_o) + 4096 (ff1)

typedef unsigned short u16;
typedef unsigned int   u32;
typedef __attribute__((ext_vector_type(8))) short s16x8;
typedef __attribute__((ext_vector_type(4))) float f32x4;

__device__ __forceinline__ u16 f2bf(float f) {
  u32 u = __builtin_bit_cast(u32, f);
  u += 0x7fffu + ((u >> 16) & 1u);
  return (u16)(u >> 16);
}

// async global->LDS, 16B per lane. HW semantics: dest = wave-uniform base + lane*16.
__device__ __forceinline__ void gl2lds16(const void* g, void* l) {
  __builtin_amdgcn_global_load_lds((__attribute__((address_space(1))) void*)(g),
                                   (__attribute__((address_space(3))) void*)(l),
                                   16, 0, 0);
}

// ---------------- RMSNorm: x fp32 [BT][DM] -> xn bf16 ----------------
__global__ __launch_bounds__(256) void rmsnorm_k(const float* __restrict__ x,
                                                 const float* __restrict__ w,
                                                 u16* __restrict__ xn) {
  const int row = blockIdx.x;
  const int t = threadIdx.x;
  const float4 v = ((const float4*)(x + (size_t)row * DM))[t];
  float ss = v.x*v.x + v.y*v.y + v.z*v.z + v.w*v.w;
  #pragma unroll
  for (int off = 32; off; off >>= 1) ss += __shfl_xor(ss, off, 64);
  __shared__ float red[4];
  if ((t & 63) == 0) red[t >> 6] = ss;
  __syncthreads();
  const float tot = red[0] + red[1] + red[2] + red[3];
  const float r = __builtin_amdgcn_rsqf(tot * (1.0f / DM) + 1.1920929e-7f);
  const float4 wv = ((const float4*)w)[t];
  u16* o = xn + (size_t)row * DM + t * 4;
  o[0] = f2bf(v.x * r * wv.x);
  o[1] = f2bf(v.y * r * wv.y);
  o[2] = f2bf(v.z * r * wv.z);
  o[3] = f2bf(v.w * r * wv.w);
}

// --- weight transpose+cvt: W fp32 [K][N] -> Wt bf16 [n][pitch] at col-offset koff ---
__global__ __launch_bounds__(256) void wtrans_k(const float* __restrict__ W,
                                                u16* __restrict__ Wt,
                                                int K, int N, int pitch, int koff) {
  __shared__ float tile[32][33];
  const int n0 = blockIdx.x * 32, k0 = blockIdx.y * 32;
  const int tx = threadIdx.x, ty = threadIdx.y;  // (32,8)
  #pragma unroll
  for (int i = 0; i < 4; ++i)
    tile[ty + i*8][tx] = W[(size_t)(k0 + ty + i*8) * N + n0 + tx];
  __syncthreads();
  #pragma unroll
  for (int i = 0; i < 4; ++i)
    Wt[(size_t)(n0 + ty + i*8) * pitch + koff + k0 + tx] = f2bf(tile[tx][ty + i*8]);
}

// ---- fused QKV+FFN1 GEMM: A=xn [4096][1024], Bt=wqkv1_t [7168][1024] ----
// col<1024 (Q): *scale -> qkb; <2048 (K): qkb; <3072 (V): transposed vtg;
// >=3072: silu -> A_cat cols 1024.. (pitch 5120)
__global__ __launch_bounds__(256, 2) void gemm_fused(const u16* __restrict__ A,
                                                     const u16* __restrict__ Bt,
                                                     u16* __restrict__ qkb,
                                                     u16* __restrict__ vtg,
                                                     u16* __restrict__ acat) {
  const int K = 1024;
  __shared__ u16 sA[128 * 32];
  __shared__ u16 sB[128 * 32];
  const int t = threadIdx.x;
  const int lane = t & 63, wave = t >> 6;
  const int quad = lane >> 4, l4 = lane & 15;
  const int wy = wave >> 1, wx = wave & 1;
  const size_t mBase = (size_t)blockIdx.y * 128;
  const size_t nBase = (size_t)blockIdx.x * 128;
  const int r  = t >> 2;
  const int c8 = (t & 3) * 8;
  const u16* Ag0 = A + (mBase + r) * K + c8;
  const u16* Ag1 = Ag0 + (size_t)64 * K;
  const u16* Bg0 = Bt + (nBase + r) * K + c8;
  const u16* Bg1 = Bg0 + (size_t)64 * K;
  char* sAb = (char*)sA + (wave << 10);
  char* sBb = (char*)sB + (wave << 10);

  f32x4 acc[4][4];
  #pragma unroll
  for (int i = 0; i < 4; ++i)
    #pragma unroll
    for (int j = 0; j < 4; ++j)
      acc[i][j] = (f32x4)0.0f;

  for (int k0 = 0; k0 < K; k0 += 32) {
    __syncthreads();
    gl2lds16(Ag0 + k0, sAb);
    gl2lds16(Ag1 + k0, sAb + 4096);
    gl2lds16(Bg0 + k0, sBb);
    gl2lds16(Bg1 + k0, sBb + 4096);
    __syncthreads();
    s16x8 af[4], bfr[4];
    #pragma unroll
    for (int i = 0; i < 4; ++i)
      af[i] = *(const s16x8*)&sA[(wy*64 + i*16 + l4) * 32 + quad*8];
    #pragma unroll
    for (int j = 0; j < 4; ++j)
      bfr[j] = *(const s16x8*)&sB[(wx*64 + j*16 + l4) * 32 + quad*8];
    #pragma unroll
    for (int i = 0; i < 4; ++i)
      #pragma unroll
      for (int j = 0; j < 4; ++j)
        acc[i][j] = __builtin_amdgcn_mfma_f32_16x16x32_bf16(af[i], bfr[j], acc[i][j], 0, 0, 0);
  }

  // block-uniform region select (boundaries 1024/2048/3072 are 128-aligned)
  #pragma unroll
  for (int i = 0; i < 4; ++i) {
    const size_t row0 = mBase + wy*64 + i*16 + quad*4;
    #pragma unroll
    for (int j = 0; j < 4; ++j) {
      const int col = (int)nBase + wx*64 + j*16 + l4;
      if (nBase < 1024) {               // Q: fold (1/sqrt(64))*log2(e)
        #pragma unroll
        for (int rg = 0; rg < 4; ++rg)
          qkb[(row0 + rg) * 2048 + col] = f2bf(acc[i][j][rg] * 0.18033688011f);
      } else if (nBase < 2048) {        // K
        #pragma unroll
        for (int rg = 0; rg < 4; ++rg)
          qkb[(row0 + rg) * 2048 + col] = f2bf(acc[i][j][rg]);
      } else if (nBase < 3072) {        // V: transposed, 4 tokens packed
        const int cv = col - 2048, hh = cv >> 6, dd = cv & 63;
        const int bb = (int)(row0 >> 11), t0 = (int)(row0 & 2047);
        ushort4 pk;
        pk.x = f2bf(acc[i][j][0]); pk.y = f2bf(acc[i][j][1]);
        pk.z = f2bf(acc[i][j][2]); pk.w = f2bf(acc[i][j][3]);
        *(ushort4*)(vtg + ((size_t)((bb*16 + hh)*64 + dd)) * 2048 + t0) = pk;
      } else {                          // FFN1: silu -> A_cat cols 1024..5119
        #pragma unroll
        for (int rg = 0; rg < 4; ++rg) {
          float v = acc[i][j][rg];
          v = v / (1.0f + __expf(-v));
          acat[(row0 + rg) * (size_t)KC + 1024 + (col - 3072)] = f2bf(v);
        }
      }
    }
  }
}

// ---- final GEMM: d_out = x + A_cat[4096][5120] * B_cat[1024][5120]^T ----
// 512 threads = 8 waves (2x4 wave tiling of the 128x128 tile); grid (8,32)=256
// blocks = exactly 1/CU, 8 waves/CU. No atomics, no split-K.
__global__ __launch_bounds__(512) void gemm_final(const u16* __restrict__ A,
                                                  const u16* __restrict__ Bt,
                                                  const float* __restrict__ x,
                                                  float* __restrict__ out) {
  __shared__ u16 sA[128 * 32];   // 8 KB
  __shared__ u16 sB[128 * 32];   // 8 KB
  const int t = threadIdx.x;
  const int lane = t & 63, wave = t >> 6;
  const int quad = lane >> 4, l4 = lane & 15;
  const int wy = wave >> 2, wx = wave & 3;   // 2x4 wave grid
  const size_t mBase = (size_t)blockIdx.y * 128;
  const size_t nBase = (size_t)blockIdx.x * 128;
  const int r  = t >> 2;          // 0..127
  const int c8 = (t & 3) * 8;
  const u16* Ag = A  + (mBase + r) * KC + c8;
  const u16* Bg = Bt + (nBase + r) * KC + c8;
  char* sAb = (char*)sA + (wave << 10);   // wave-uniform LDS base
  char* sBb = (char*)sB + (wave << 10);

  f32x4 acc[4][2];
  #pragma unroll
  for (int i = 0; i < 4; ++i)
    #pragma unroll
    for (int j = 0; j < 2; ++j)
      acc[i][j] = (f32x4)0.0f;

  for (int k0 = 0; k0 < KC; k0 += 32) {
    __syncthreads();
    gl2lds16(Ag + k0, sAb);
    gl2lds16(Bg + k0, sBb);
    __syncthreads();
    s16x8 af[4], bfr[2];
    #pragma unroll
    for (int i = 0; i < 4; ++i)
      af[i] = *(const s16x8*)&sA[(wy*64 + i*16 + l4) * 32 + quad*8];
    #pragma unroll
    for (int j = 0; j < 2; ++j)
      bfr[j] = *(const s16x8*)&sB[(wx*32 + j*16 + l4) * 32 + quad*8];
    #pragma unroll
    for (int i = 0; i < 4; ++i)
      #pragma unroll
      for (int j = 0; j < 2; ++j)
        acc[i][j] = __builtin_amdgcn_mfma_f32_16x16x32_bf16(af[i], bfr[j], acc[i][j], 0, 0, 0);
  }

  #pragma unroll
  for (int i = 0; i < 4; ++i) {
    const size_t row0 = mBase + wy*64 + i*16 + quad*4;
    #pragma unroll
    for (int j = 0; j < 2; ++j) {
      const int col = (int)nBase + wx*32 + j*16 + l4;
      #pragma unroll
      for (int rg = 0; rg < 4; ++rg) {
        const size_t idx = (row0 + rg) * (size_t)DM + col;
        out[idx] = x[idx] + acc[i][j][rg];
      }
    }
  }
}

// ------- causal flash attention, fixed-max, in-block split-K=2 over waves -------
// writes bf16 into A_cat cols 0..1023 (pitch 5120)
__global__ __launch_bounds__(128) void attn_k(const u16* __restrict__ qk,
                                              const u16* __restrict__ vtg,
                                              u16* __restrict__ acat) {
  const int bh = blockIdx.x, b = bh >> 4, h = bh & 15;
  const int qt = 63 - blockIdx.y;
  const int qw = qt * 32;
  const int wave = threadIdx.x >> 6, lane = threadIdx.x & 63;
  const int quad = lane >> 4, l4 = lane & 15;
  const u16* Qp = qk + (size_t)b * TT * 2048 + h * HD;
  const u16* Kp = Qp + 1024;
  const u16* Vp = vtg + (size_t)bh * 64 * 2048;

  __shared__ u16 Pb[2][32][72];
  __shared__ float Ob[32][68];
  __shared__ float Lb[32];

  s16x8 qf[2][2];
  #pragma unroll
  for (int mi = 0; mi < 2; ++mi)
    #pragma unroll
    for (int kf = 0; kf < 2; ++kf)
      qf[mi][kf] = *(const s16x8*)(Qp + (size_t)(qw + mi*16 + l4) * 2048 + kf*32 + quad*8);

  const s16x8 ones = {0x3F80,0x3F80,0x3F80,0x3F80,0x3F80,0x3F80,0x3F80,0x3F80};

  f32x4 o[2][4];
  f32x4 lacc[2];
  #pragma unroll
  for (int mi = 0; mi < 2; ++mi) {
    lacc[mi] = (f32x4)0.0f;
    #pragma unroll
    for (int ni = 0; ni < 4; ++ni) o[mi][ni] = (f32x4)0.0f;
  }

  const int n   = (qt + 2) >> 1;
  const int n0  = (n + 1) >> 1;
  const int kt0 = wave ? n0 : 0;
  const int kt1 = wave ? n : n0;

  for (int kt = kt0; kt < kt1; ++kt) {
    const int k0 = kt * 64;

    f32x4 st[4][2];
    #pragma unroll
    for (int nj = 0; nj < 4; ++nj) {
      const u16* kr = Kp + (size_t)(k0 + nj*16 + l4) * 2048 + quad*8;
      const s16x8 kf0 = *(const s16x8*)kr;
      const s16x8 kf1 = *(const s16x8*)(kr + 32);
      #pragma unroll
      for (int mi = 0; mi < 2; ++mi) {
        f32x4 a = (f32x4)0.0f;
        a = __builtin_amdgcn_mfma_f32_16x16x32_bf16(kf0, qf[mi][0], a, 0, 0, 0);
        a = __builtin_amdgcn_mfma_f32_16x16x32_bf16(kf1, qf[mi][1], a, 0, 0, 0);
        st[nj][mi] = a;
      }
    }

    s16x8 vb[2][4];
    #pragma unroll
    for (int kf2 = 0; kf2 < 2; ++kf2)
      #pragma unroll
      for (int ni = 0; ni < 4; ++ni)
        vb[kf2][ni] = *(const s16x8*)(Vp + (size_t)(ni*16 + l4) * 2048 + k0 + kf2*32 + quad*8);

    if (k0 + 63 > qw) {
      #pragma unroll
      for (int nj = 0; nj < 4; ++nj)
        #pragma unroll
        for (int mi = 0; mi < 2; ++mi)
          #pragma unroll
          for (int rg = 0; rg < 4; ++rg) {
            const int key = k0 + nj*16 + quad*4 + rg;
            const int q   = qw + mi*16 + l4;
            if (key > q) st[nj][mi][rg] = -1e30f;
          }
    }

    #pragma unroll
    for (int nj = 0; nj < 4; ++nj)
      #pragma unroll
      for (int mi = 0; mi < 2; ++mi) {
        float p0 = __builtin_amdgcn_exp2f(st[nj][mi][0]);
        float p1 = __builtin_amdgcn_exp2f(st[nj][mi][1]);
        float p2 = __builtin_amdgcn_exp2f(st[nj][mi][2]);
        float p3 = __builtin_amdgcn_exp2f(st[nj][mi][3]);
        uint2 w;
        w.x = __builtin_amdgcn_perm(__builtin_bit_cast(u32, p1),
                                    __builtin_bit_cast(u32, p0), 0x07060302u);
        w.y = __builtin_amdgcn_perm(__builtin_bit_cast(u32, p3),
                                    __builtin_bit_cast(u32, p2), 0x07060302u);
        *(uint2*)&Pb[wave][mi*16 + l4][nj*16 + quad*4] = w;
      }

    #pragma unroll
    for (int kf2 = 0; kf2 < 2; ++kf2) {
      s16x8 pa[2];
      #pragma unroll
      for (int mi = 0; mi < 2; ++mi)
        pa[mi] = *(const s16x8*)&Pb[wave][mi*16 + l4][kf2*32 + quad*8];
      #pragma unroll
      for (int mi = 0; mi < 2; ++mi) {
        lacc[mi] = __builtin_amdgcn_mfma_f32_16x16x32_bf16(pa[mi], ones, lacc[mi], 0, 0, 0);
        #pragma unroll
        for (int ni = 0; ni < 4; ++ni)
          o[mi][ni] = __builtin_amdgcn_mfma_f32_16x16x32_bf16(pa[mi], vb[kf2][ni], o[mi][ni], 0, 0, 0);
      }
    }
  }

  if (wave == 1) {
    #pragma unroll
    for (int mi = 0; mi < 2; ++mi)
      #pragma unroll
      for (int rg = 0; rg < 4; ++rg) {
        const int row = mi*16 + quad*4 + rg;
        #pragma unroll
        for (int ni = 0; ni < 4; ++ni) Ob[row][ni*16 + l4] = o[mi][ni][rg];
        if (l4 == 0) Lb[row] = lacc[mi][rg];
      }
  }
  __syncthreads();
  if (wave == 0) {
    #pragma unroll
    for (int mi = 0; mi < 2; ++mi)
      #pragma unroll
      for (int rg = 0; rg < 4; ++rg) {
        const int row = mi*16 + quad*4 + rg;
        const float inv = 1.0f / (lacc[mi][rg] + Lb[row]);
        #pragma unroll
        for (int ni = 0; ni < 4; ++ni)
          Pb[0][row][ni*16 + l4] = f2bf((o[mi][ni][rg] + Ob[row][ni*16 + l4]) * inv);
      }
    #pragma unroll
    for (int it = 0; it < 4; ++it) {
      const int row = it*8 + (lane >> 3);
      const int c0  = (lane & 7) * 8;
      const s16x8 pk = *(const s16x8*)&Pb[0][row][c0];
      *(s16x8*)(acat + ((size_t)b * TT + qw + row) * KC + h*HD + c0) = pk;
    }
  }
}

extern "C" void kernel_launch(void* const* d_in, const int* in_sizes, int n_in,
                              void* d_out, int out_size, void* d_ws, size_t ws_size,
                              hipStream_t stream) {
  (void)in_sizes; (void)n_in; (void)out_size; (void)ws_size;
  const float* x  = (const float*)d_in[0];
  const float* nw = (const float*)d_in[1];
  const float* Wq = (const float*)d_in[2];
  const float* Wk = (const float*)d_in[3];
  const float* Wv = (const float*)d_in[4];
  const float* Wo = (const float*)d_in[5];
  const float* W1 = (const float*)d_in[6];
  const float* W2 = (const float*)d_in[7];

  char* ws = (char*)d_ws;
  u16*   xn      = (u16*)(ws);                          //  8 MB  [4096][1024]
  u16*   wqkv1_t = (u16*)(ws + ((size_t)8  << 20));     // 14 MB  [7168][1024] Wq|Wk|Wv|W1 ^T
  u16*   bcat    = (u16*)(ws + ((size_t)22 << 20));     // 10 MB  [1024][5120] Wo^T|W2^T
  u16*   qkb     = (u16*)(ws + ((size_t)32 << 20));     // 16 MB  [4096][2048] (q|k)
  u16*   vtg     = (u16*)(ws + ((size_t)48 << 20));     //  8 MB  [32][64][2048] V^T
  u16*   acat    = (u16*)(ws + ((size_t)56 << 20));     // 40 MB  [4096][5120] attn_o|ff1
  float* dout    = (float*)d_out;                       // 16 MB  [4096][1024] fp32

  rmsnorm_k<<<BT, 256, 0, stream>>>(x, nw, xn);
  const dim3 tb(32, 8);
  wtrans_k<<<dim3(32, 32),  tb, 0, stream>>>(Wq, wqkv1_t,                      1024, 1024, 1024, 0);
  wtrans_k<<<dim3(32, 32),  tb, 0, stream>>>(Wk, wqkv1_t + (size_t)1024*1024,  1024, 1024, 1024, 0);
  wtrans_k<<<dim3(32, 32),  tb, 0, stream>>>(Wv, wqkv1_t + (size_t)2048*1024,  1024, 1024, 1024, 0);
  wtrans_k<<<dim3(128, 32), tb, 0, stream>>>(W1, wqkv1_t + (size_t)3072*1024,  1024, 4096, 1024, 0);
  wtrans_k<<<dim3(32, 32),  tb, 0, stream>>>(Wo, bcat,                         1024, 1024, 5120, 0);
  wtrans_k<<<dim3(32, 128), tb, 0, stream>>>(W2, bcat,                         4096, 1024, 5120, 1024);

  gemm_fused<<<dim3(56, 32), 256, 0, stream>>>(xn, wqkv1_t, qkb, vtg, acat);
  attn_k<<<dim3(32, 64), 128, 0, stream>>>(qkb, vtg, acat);
  gemm_final<<<dim3(8, 32), 512, 0, stream>>>(acat, bcat, x, dout);
}

// Round 8
// 373.854 us; speedup vs baseline: 1.0213x; 1.0091x over previous
//
#include <hip/hip_runtime.h>

#define DM   1024
#define DFF  4096
#define NH   16
#define HD   64
#define TT   2048
#define BT   4096   // B*T
#define KC   5120   // concat-K: 1024 (attn_o) + 4096 (ff1)

typedef unsigned short u16;
typedef unsigned int   u32;
typedef __attribute__((ext_vector_type(8))) short s16x8;
typedef __attribute__((ext_vector_type(4))) float f32x4;

__device__ __forceinline__ u16 f2bf(float f) {
  u32 u = __builtin_bit_cast(u32, f);
  u += 0x7fffu + ((u >> 16) & 1u);
  return (u16)(u >> 16);
}

// async global->LDS, 16B per lane. HW semantics: dest = wave-uniform base + lane*16.
__device__ __forceinline__ void gl2lds16(const void* g, void* l) {
  __builtin_amdgcn_global_load_lds((__attribute__((address_space(1))) void*)(g),
                                   (__attribute__((address_space(3))) void*)(l),
                                   16, 0, 0);
}

// ---------------- RMSNorm: x fp32 [BT][DM] -> xn bf16 ----------------
__global__ __launch_bounds__(256) void rmsnorm_k(const float* __restrict__ x,
                                                 const float* __restrict__ w,
                                                 u16* __restrict__ xn) {
  const int row = blockIdx.x;
  const int t = threadIdx.x;
  const float4 v = ((const float4*)(x + (size_t)row * DM))[t];
  float ss = v.x*v.x + v.y*v.y + v.z*v.z + v.w*v.w;
  #pragma unroll
  for (int off = 32; off; off >>= 1) ss += __shfl_xor(ss, off, 64);
  __shared__ float red[4];
  if ((t & 63) == 0) red[t >> 6] = ss;
  __syncthreads();
  const float tot = red[0] + red[1] + red[2] + red[3];
  const float r = __builtin_amdgcn_rsqf(tot * (1.0f / DM) + 1.1920929e-7f);
  const float4 wv = ((const float4*)w)[t];
  u16* o = xn + (size_t)row * DM + t * 4;
  o[0] = f2bf(v.x * r * wv.x);
  o[1] = f2bf(v.y * r * wv.y);
  o[2] = f2bf(v.z * r * wv.z);
  o[3] = f2bf(v.w * r * wv.w);
}

// --- weight transpose+cvt: W fp32 [K][N] -> Wt bf16 [n][pitch] at col-offset koff ---
__global__ __launch_bounds__(256) void wtrans_k(const float* __restrict__ W,
                                                u16* __restrict__ Wt,
                                                int K, int N, int pitch, int koff) {
  __shared__ float tile[32][33];
  const int n0 = blockIdx.x * 32, k0 = blockIdx.y * 32;
  const int tx = threadIdx.x, ty = threadIdx.y;  // (32,8)
  #pragma unroll
  for (int i = 0; i < 4; ++i)
    tile[ty + i*8][tx] = W[(size_t)(k0 + ty + i*8) * N + n0 + tx];
  __syncthreads();
  #pragma unroll
  for (int i = 0; i < 4; ++i)
    Wt[(size_t)(n0 + ty + i*8) * pitch + koff + k0 + tx] = f2bf(tile[tx][ty + i*8]);
}

// ---- fused QKV+FFN1 GEMM, double-buffered: A=xn [4096][1024], Bt [7168][1024] ----
// col<1024 (Q): *scale -> qkb; <2048 (K): qkb; <3072 (V): transposed vtg;
// >=3072: silu -> A_cat cols 1024.. (pitch 5120)
__global__ __launch_bounds__(256, 2) void gemm_fused(const u16* __restrict__ A,
                                                     const u16* __restrict__ Bt,
                                                     u16* __restrict__ qkb,
                                                     u16* __restrict__ vtg,
                                                     u16* __restrict__ acat) {
  const int K = 1024;
  __shared__ u16 sA[2 * 128 * 32];   // 2 buffers x 8 KB
  __shared__ u16 sB[2 * 128 * 32];
  const int t = threadIdx.x;
  const int lane = t & 63, wave = t >> 6;
  const int quad = lane >> 4, l4 = lane & 15;
  const int wy = wave >> 1, wx = wave & 1;
  const size_t mBase = (size_t)blockIdx.y * 128;
  const size_t nBase = (size_t)blockIdx.x * 128;
  const int r  = t >> 2;          // 0..63
  const int c8 = (t & 3) * 8;
  const u16* Ag0 = A + (mBase + r) * K + c8;
  const u16* Ag1 = Ag0 + (size_t)64 * K;
  const u16* Bg0 = Bt + (nBase + r) * K + c8;
  const u16* Bg1 = Bg0 + (size_t)64 * K;
  char* sAb = (char*)sA + (wave << 10);
  char* sBb = (char*)sB + (wave << 10);

  f32x4 acc[4][4];
  #pragma unroll
  for (int i = 0; i < 4; ++i)
    #pragma unroll
    for (int j = 0; j < 4; ++j)
      acc[i][j] = (f32x4)0.0f;

  auto issue = [&](int bf, int k0) {
    gl2lds16(Ag0 + k0, sAb + bf*8192);
    gl2lds16(Ag1 + k0, sAb + bf*8192 + 4096);
    gl2lds16(Bg0 + k0, sBb + bf*8192);
    gl2lds16(Bg1 + k0, sBb + bf*8192 + 4096);
  };

  issue(0, 0);
  for (int kt = 0; kt < 32; ++kt) {
    const int bf = kt & 1;
    __syncthreads();                        // drains buf[bf] loads (in flight since kt-1)
    if (kt + 1 < 32) issue(bf ^ 1, (kt + 1) * 32);
    const u16* pA = sA + bf * 4096;
    const u16* pB = sB + bf * 4096;
    s16x8 af[4], bfr[4];
    #pragma unroll
    for (int i = 0; i < 4; ++i)
      af[i] = *(const s16x8*)&pA[(wy*64 + i*16 + l4) * 32 + quad*8];
    #pragma unroll
    for (int j = 0; j < 4; ++j)
      bfr[j] = *(const s16x8*)&pB[(wx*64 + j*16 + l4) * 32 + quad*8];
    #pragma unroll
    for (int i = 0; i < 4; ++i)
      #pragma unroll
      for (int j = 0; j < 4; ++j)
        acc[i][j] = __builtin_amdgcn_mfma_f32_16x16x32_bf16(af[i], bfr[j], acc[i][j], 0, 0, 0);
  }

  // block-uniform region select (boundaries 1024/2048/3072 are 128-aligned)
  #pragma unroll
  for (int i = 0; i < 4; ++i) {
    const size_t row0 = mBase + wy*64 + i*16 + quad*4;
    #pragma unroll
    for (int j = 0; j < 4; ++j) {
      const int col = (int)nBase + wx*64 + j*16 + l4;
      if (nBase < 1024) {               // Q: fold (1/sqrt(64))*log2(e)
        #pragma unroll
        for (int rg = 0; rg < 4; ++rg)
          qkb[(row0 + rg) * 2048 + col] = f2bf(acc[i][j][rg] * 0.18033688011f);
      } else if (nBase < 2048) {        // K
        #pragma unroll
        for (int rg = 0; rg < 4; ++rg)
          qkb[(row0 + rg) * 2048 + col] = f2bf(acc[i][j][rg]);
      } else if (nBase < 3072) {        // V: transposed, 4 tokens packed
        const int cv = col - 2048, hh = cv >> 6, dd = cv & 63;
        const int bb = (int)(row0 >> 11), t0 = (int)(row0 & 2047);
        ushort4 pk;
        pk.x = f2bf(acc[i][j][0]); pk.y = f2bf(acc[i][j][1]);
        pk.z = f2bf(acc[i][j][2]); pk.w = f2bf(acc[i][j][3]);
        *(ushort4*)(vtg + ((size_t)((bb*16 + hh)*64 + dd)) * 2048 + t0) = pk;
      } else {                          // FFN1: silu -> A_cat cols 1024..5119
        #pragma unroll
        for (int rg = 0; rg < 4; ++rg) {
          float v = acc[i][j][rg];
          v = v / (1.0f + __expf(-v));
          acat[(row0 + rg) * (size_t)KC + 1024 + (col - 3072)] = f2bf(v);
        }
      }
    }
  }
}

// ---- final GEMM: d_out = x + A_cat[4096][5120] * B_cat[1024][5120]^T ----
// 512 threads = 8 waves (2x4 wave grid). BK=64 as two [128][32] slabs,
// double-buffered (64 KB LDS), prefetch next tile right after the single
// per-iter barrier so loads have a full compute phase in flight.
__global__ __launch_bounds__(512) void gemm_final(const u16* __restrict__ A,
                                                  const u16* __restrict__ Bt,
                                                  const float* __restrict__ x,
                                                  float* __restrict__ out) {
  __shared__ u16 sA[2 * 2 * 128 * 32];   // [buf][slab][128][32] = 32 KB
  __shared__ u16 sB[2 * 2 * 128 * 32];
  const int t = threadIdx.x;
  const int lane = t & 63, wave = t >> 6;
  const int quad = lane >> 4, l4 = lane & 15;
  const int wy = wave >> 2, wx = wave & 3;   // 2x4 wave grid
  const size_t mBase = (size_t)blockIdx.y * 128;
  const size_t nBase = (size_t)blockIdx.x * 128;
  const int r  = t >> 2;          // 0..127
  const int c8 = (t & 3) * 8;
  const u16* Ag = A  + (mBase + r) * KC + c8;
  const u16* Bg = Bt + (nBase + r) * KC + c8;
  char* sAw = (char*)sA + (wave << 10);   // wave rows r = wave*16..+15
  char* sBw = (char*)sB + (wave << 10);

  f32x4 acc[4][2];
  #pragma unroll
  for (int i = 0; i < 4; ++i)
    #pragma unroll
    for (int j = 0; j < 2; ++j)
      acc[i][j] = (f32x4)0.0f;

  auto issue = [&](int bf, int k0) {
    gl2lds16(Ag + k0,      sAw + bf*16384);
    gl2lds16(Ag + k0 + 32, sAw + bf*16384 + 8192);
    gl2lds16(Bg + k0,      sBw + bf*16384);
    gl2lds16(Bg + k0 + 32, sBw + bf*16384 + 8192);
  };

  issue(0, 0);
  const int NIT = KC / 64;   // 80
  for (int kt = 0; kt < NIT; ++kt) {
    const int bf = kt & 1;
    __syncthreads();                        // drains buf[bf] (in flight since kt-1)
    if (kt + 1 < NIT) issue(bf ^ 1, (kt + 1) * 64);
    #pragma unroll
    for (int s = 0; s < 2; ++s) {
      const u16* pA = sA + (bf*2 + s) * 4096;
      const u16* pB = sB + (bf*2 + s) * 4096;
      s16x8 af[4], bfr[2];
      #pragma unroll
      for (int i = 0; i < 4; ++i)
        af[i] = *(const s16x8*)&pA[(wy*64 + i*16 + l4) * 32 + quad*8];
      #pragma unroll
      for (int j = 0; j < 2; ++j)
        bfr[j] = *(const s16x8*)&pB[(wx*32 + j*16 + l4) * 32 + quad*8];
      #pragma unroll
      for (int i = 0; i < 4; ++i)
        #pragma unroll
        for (int j = 0; j < 2; ++j)
          acc[i][j] = __builtin_amdgcn_mfma_f32_16x16x32_bf16(af[i], bfr[j], acc[i][j], 0, 0, 0);
    }
  }

  #pragma unroll
  for (int i = 0; i < 4; ++i) {
    const size_t row0 = mBase + wy*64 + i*16 + quad*4;
    #pragma unroll
    for (int j = 0; j < 2; ++j) {
      const int col = (int)nBase + wx*32 + j*16 + l4;
      #pragma unroll
      for (int rg = 0; rg < 4; ++rg) {
        const size_t idx = (row0 + rg) * (size_t)DM + col;
        out[idx] = x[idx] + acc[i][j][rg];
      }
    }
  }
}

// ------- causal flash attention, fixed-max, in-block split-K=2 over waves -------
// writes bf16 into A_cat cols 0..1023 (pitch 5120)
__global__ __launch_bounds__(128) void attn_k(const u16* __restrict__ qk,
                                              const u16* __restrict__ vtg,
                                              u16* __restrict__ acat) {
  const int bh = blockIdx.x, b = bh >> 4, h = bh & 15;
  const int qt = 63 - blockIdx.y;
  const int qw = qt * 32;
  const int wave = threadIdx.x >> 6, lane = threadIdx.x & 63;
  const int quad = lane >> 4, l4 = lane & 15;
  const u16* Qp = qk + (size_t)b * TT * 2048 + h * HD;
  const u16* Kp = Qp + 1024;
  const u16* Vp = vtg + (size_t)bh * 64 * 2048;

  __shared__ u16 Pb[2][32][72];
  __shared__ float Ob[32][68];
  __shared__ float Lb[32];

  s16x8 qf[2][2];
  #pragma unroll
  for (int mi = 0; mi < 2; ++mi)
    #pragma unroll
    for (int kf = 0; kf < 2; ++kf)
      qf[mi][kf] = *(const s16x8*)(Qp + (size_t)(qw + mi*16 + l4) * 2048 + kf*32 + quad*8);

  const s16x8 ones = {0x3F80,0x3F80,0x3F80,0x3F80,0x3F80,0x3F80,0x3F80,0x3F80};

  f32x4 o[2][4];
  f32x4 lacc[2];
  #pragma unroll
  for (int mi = 0; mi < 2; ++mi) {
    lacc[mi] = (f32x4)0.0f;
    #pragma unroll
    for (int ni = 0; ni < 4; ++ni) o[mi][ni] = (f32x4)0.0f;
  }

  const int n   = (qt + 2) >> 1;
  const int n0  = (n + 1) >> 1;
  const int kt0 = wave ? n0 : 0;
  const int kt1 = wave ? n : n0;

  for (int kt = kt0; kt < kt1; ++kt) {
    const int k0 = kt * 64;

    f32x4 st[4][2];
    #pragma unroll
    for (int nj = 0; nj < 4; ++nj) {
      const u16* kr = Kp + (size_t)(k0 + nj*16 + l4) * 2048 + quad*8;
      const s16x8 kf0 = *(const s16x8*)kr;
      const s16x8 kf1 = *(const s16x8*)(kr + 32);
      #pragma unroll
      for (int mi = 0; mi < 2; ++mi) {
        f32x4 a = (f32x4)0.0f;
        a = __builtin_amdgcn_mfma_f32_16x16x32_bf16(kf0, qf[mi][0], a, 0, 0, 0);
        a = __builtin_amdgcn_mfma_f32_16x16x32_bf16(kf1, qf[mi][1], a, 0, 0, 0);
        st[nj][mi] = a;
      }
    }

    s16x8 vb[2][4];
    #pragma unroll
    for (int kf2 = 0; kf2 < 2; ++kf2)
      #pragma unroll
      for (int ni = 0; ni < 4; ++ni)
        vb[kf2][ni] = *(const s16x8*)(Vp + (size_t)(ni*16 + l4) * 2048 + k0 + kf2*32 + quad*8);

    if (k0 + 63 > qw) {
      #pragma unroll
      for (int nj = 0; nj < 4; ++nj)
        #pragma unroll
        for (int mi = 0; mi < 2; ++mi)
          #pragma unroll
          for (int rg = 0; rg < 4; ++rg) {
            const int key = k0 + nj*16 + quad*4 + rg;
            const int q   = qw + mi*16 + l4;
            if (key > q) st[nj][mi][rg] = -1e30f;
          }
    }

    #pragma unroll
    for (int nj = 0; nj < 4; ++nj)
      #pragma unroll
      for (int mi = 0; mi < 2; ++mi) {
        float p0 = __builtin_amdgcn_exp2f(st[nj][mi][0]);
        float p1 = __builtin_amdgcn_exp2f(st[nj][mi][1]);
        float p2 = __builtin_amdgcn_exp2f(st[nj][mi][2]);
        float p3 = __builtin_amdgcn_exp2f(st[nj][mi][3]);
        uint2 w;
        w.x = __builtin_amdgcn_perm(__builtin_bit_cast(u32, p1),
                                    __builtin_bit_cast(u32, p0), 0x07060302u);
        w.y = __builtin_amdgcn_perm(__builtin_bit_cast(u32, p3),
                                    __builtin_bit_cast(u32, p2), 0x07060302u);
        *(uint2*)&Pb[wave][mi*16 + l4][nj*16 + quad*4] = w;
      }

    #pragma unroll
    for (int kf2 = 0; kf2 < 2; ++kf2) {
      s16x8 pa[2];
      #pragma unroll
      for (int mi = 0; mi < 2; ++mi)
        pa[mi] = *(const s16x8*)&Pb[wave][mi*16 + l4][kf2*32 + quad*8];
      #pragma unroll
      for (int mi = 0; mi < 2; ++mi) {
        lacc[mi] = __builtin_amdgcn_mfma_f32_16x16x32_bf16(pa[mi], ones, lacc[mi], 0, 0, 0);
        #pragma unroll
        for (int ni = 0; ni < 4; ++ni)
          o[mi][ni] = __builtin_amdgcn_mfma_f32_16x16x32_bf16(pa[mi], vb[kf2][ni], o[mi][ni], 0, 0, 0);
      }
    }
  }

  if (wave == 1) {
    #pragma unroll
    for (int mi = 0; mi < 2; ++mi)
      #pragma unroll
      for (int rg = 0; rg < 4; ++rg) {
        const int row = mi*16 + quad*4 + rg;
        #pragma unroll
        for (int ni = 0; ni < 4; ++ni) Ob[row][ni*16 + l4] = o[mi][ni][rg];
        if (l4 == 0) Lb[row] = lacc[mi][rg];
      }
  }
  __syncthreads();
  if (wave == 0) {
    #pragma unroll
    for (int mi = 0; mi < 2; ++mi)
      #pragma unroll
      for (int rg = 0; rg < 4; ++rg) {
        const int row = mi*16 + quad*4 + rg;
        const float inv = 1.0f / (lacc[mi][rg] + Lb[row]);
        #pragma unroll
        for (int ni = 0; ni < 4; ++ni)
          Pb[0][row][ni*16 + l4] = f2bf((o[mi][ni][rg] + Ob[row][ni*16 + l4]) * inv);
      }
    #pragma unroll
    for (int it = 0; it < 4; ++it) {
      const int row = it*8 + (lane >> 3);
      const int c0  = (lane & 7) * 8;
      const s16x8 pk = *(const s16x8*)&Pb[0][row][c0];
      *(s16x8*)(acat + ((size_t)b * TT + qw + row) * KC + h*HD + c0) = pk;
    }
  }
}

extern "C" void kernel_launch(void* const* d_in, const int* in_sizes, int n_in,
                              void* d_out, int out_size, void* d_ws, size_t ws_size,
                              hipStream_t stream) {
  (void)in_sizes; (void)n_in; (void)out_size; (void)ws_size;
  const float* x  = (const float*)d_in[0];
  const float* nw = (const float*)d_in[1];
  const float* Wq = (const float*)d_in[2];
  const float* Wk = (const float*)d_in[3];
  const float* Wv = (const float*)d_in[4];
  const float* Wo = (const float*)d_in[5];
  const float* W1 = (const float*)d_in[6];
  const float* W2 = (const float*)d_in[7];

  char* ws = (char*)d_ws;
  u16*   xn      = (u16*)(ws);                          //  8 MB  [4096][1024]
  u16*   wqkv1_t = (u16*)(ws + ((size_t)8  << 20));     // 14 MB  [7168][1024] Wq|Wk|Wv|W1 ^T
  u16*   bcat    = (u16*)(ws + ((size_t)22 << 20));     // 10 MB  [1024][5120] Wo^T|W2^T
  u16*   qkb     = (u16*)(ws + ((size_t)32 << 20));     // 16 MB  [4096][2048] (q|k)
  u16*   vtg     = (u16*)(ws + ((size_t)48 << 20));     //  8 MB  [32][64][2048] V^T
  u16*   acat    = (u16*)(ws + ((size_t)56 << 20));     // 40 MB  [4096][5120] attn_o|ff1
  float* dout    = (float*)d_out;                       // 16 MB  [4096][1024] fp32

  rmsnorm_k<<<BT, 256, 0, stream>>>(x, nw, xn);
  const dim3 tb(32, 8);
  wtrans_k<<<dim3(32, 32),  tb, 0, stream>>>(Wq, wqkv1_t,                      1024, 1024, 1024, 0);
  wtrans_k<<<dim3(32, 32),  tb, 0, stream>>>(Wk, wqkv1_t + (size_t)1024*1024,  1024, 1024, 1024, 0);
  wtrans_k<<<dim3(32, 32),  tb, 0, stream>>>(Wv, wqkv1_t + (size_t)2048*1024,  1024, 1024, 1024, 0);
  wtrans_k<<<dim3(128, 32), tb, 0, stream>>>(W1, wqkv1_t + (size_t)3072*1024,  1024, 4096, 1024, 0);
  wtrans_k<<<dim3(32, 32),  tb, 0, stream>>>(Wo, bcat,                         1024, 1024, 5120, 0);
  wtrans_k<<<dim3(32, 128), tb, 0, stream>>>(W2, bcat,                         4096, 1024, 5120, 1024);

  gemm_fused<<<dim3(56, 32), 256, 0, stream>>>(xn, wqkv1_t, qkb, vtg, acat);
  attn_k<<<dim3(32, 64), 128, 0, stream>>>(qkb, vtg, acat);
  gemm_final<<<dim3(8, 32), 512, 0, stream>>>(acat, bcat, x, dout);
}

// Round 9
// 359.174 us; speedup vs baseline: 1.0630x; 1.0409x over previous
//
#include <hip/hip_runtime.h>

#define DM   1024
#define DFF  4096
#define NH   16
#define HD   64
#define TT   2048
#define BT   4096   // B*T
#define KC   5120   // concat-K: 1024 (attn_o) + 4096 (ff1)

typedef unsigned short u16;
typedef unsigned int   u32;
typedef __attribute__((ext_vector_type(8))) short s16x8;
typedef __attribute__((ext_vector_type(4))) float f32x4;

__device__ __forceinline__ u16 f2bf(float f) {
  u32 u = __builtin_bit_cast(u32, f);
  u += 0x7fffu + ((u >> 16) & 1u);
  return (u16)(u >> 16);
}

// async global->LDS, 16B per lane. HW semantics: dest = wave-uniform base + lane*16.
__device__ __forceinline__ void gl2lds16(const void* g, void* l) {
  __builtin_amdgcn_global_load_lds((__attribute__((address_space(1))) void*)(g),
                                   (__attribute__((address_space(3))) void*)(l),
                                   16, 0, 0);
}

// ---------------- RMSNorm: x fp32 [BT][DM] -> xn bf16 ----------------
__global__ __launch_bounds__(256) void rmsnorm_k(const float* __restrict__ x,
                                                 const float* __restrict__ w,
                                                 u16* __restrict__ xn) {
  const int row = blockIdx.x;
  const int t = threadIdx.x;
  const float4 v = ((const float4*)(x + (size_t)row * DM))[t];
  float ss = v.x*v.x + v.y*v.y + v.z*v.z + v.w*v.w;
  #pragma unroll
  for (int off = 32; off; off >>= 1) ss += __shfl_xor(ss, off, 64);
  __shared__ float red[4];
  if ((t & 63) == 0) red[t >> 6] = ss;
  __syncthreads();
  const float tot = red[0] + red[1] + red[2] + red[3];
  const float r = __builtin_amdgcn_rsqf(tot * (1.0f / DM) + 1.1920929e-7f);
  const float4 wv = ((const float4*)w)[t];
  u16* o = xn + (size_t)row * DM + t * 4;
  o[0] = f2bf(v.x * r * wv.x);
  o[1] = f2bf(v.y * r * wv.y);
  o[2] = f2bf(v.z * r * wv.z);
  o[3] = f2bf(v.w * r * wv.w);
}

// --- weight transpose+cvt: W fp32 [K][N] -> Wt bf16 [n][pitch] at col-offset koff ---
__global__ __launch_bounds__(256) void wtrans_k(const float* __restrict__ W,
                                                u16* __restrict__ Wt,
                                                int K, int N, int pitch, int koff) {
  __shared__ float tile[32][33];
  const int n0 = blockIdx.x * 32, k0 = blockIdx.y * 32;
  const int tx = threadIdx.x, ty = threadIdx.y;  // (32,8)
  #pragma unroll
  for (int i = 0; i < 4; ++i)
    tile[ty + i*8][tx] = W[(size_t)(k0 + ty + i*8) * N + n0 + tx];
  __syncthreads();
  #pragma unroll
  for (int i = 0; i < 4; ++i)
    Wt[(size_t)(n0 + ty + i*8) * pitch + koff + k0 + tx] = f2bf(tile[tx][ty + i*8]);
}

// ---- fused QKV+FFN1 GEMM, double-buffered: A=xn [4096][1024], Bt [7168][1024] ----
// col<1024 (Q): *scale -> qkb; <2048 (K): qkb; <3072 (V): transposed vtg;
// >=3072: silu -> A_cat cols 1024.. (pitch 5120)
__global__ __launch_bounds__(256, 2) void gemm_fused(const u16* __restrict__ A,
                                                     const u16* __restrict__ Bt,
                                                     u16* __restrict__ qkb,
                                                     u16* __restrict__ vtg,
                                                     u16* __restrict__ acat) {
  const int K = 1024;
  __shared__ u16 sA[2 * 128 * 32];   // 2 buffers x 8 KB
  __shared__ u16 sB[2 * 128 * 32];
  const int t = threadIdx.x;
  const int lane = t & 63, wave = t >> 6;
  const int quad = lane >> 4, l4 = lane & 15;
  const int wy = wave >> 1, wx = wave & 1;
  const size_t mBase = (size_t)blockIdx.y * 128;
  const size_t nBase = (size_t)blockIdx.x * 128;
  const int r  = t >> 2;          // 0..63
  const int c8 = (t & 3) * 8;
  const u16* Ag0 = A + (mBase + r) * K + c8;
  const u16* Ag1 = Ag0 + (size_t)64 * K;
  const u16* Bg0 = Bt + (nBase + r) * K + c8;
  const u16* Bg1 = Bg0 + (size_t)64 * K;
  char* sAb = (char*)sA + (wave << 10);
  char* sBb = (char*)sB + (wave << 10);

  f32x4 acc[4][4];
  #pragma unroll
  for (int i = 0; i < 4; ++i)
    #pragma unroll
    for (int j = 0; j < 4; ++j)
      acc[i][j] = (f32x4)0.0f;

  auto issue = [&](int bf, int k0) {
    gl2lds16(Ag0 + k0, sAb + bf*8192);
    gl2lds16(Ag1 + k0, sAb + bf*8192 + 4096);
    gl2lds16(Bg0 + k0, sBb + bf*8192);
    gl2lds16(Bg1 + k0, sBb + bf*8192 + 4096);
  };

  issue(0, 0);
  for (int kt = 0; kt < 32; ++kt) {
    const int bf = kt & 1;
    __syncthreads();                        // drains buf[bf] loads (in flight since kt-1)
    if (kt + 1 < 32) issue(bf ^ 1, (kt + 1) * 32);
    const u16* pA = sA + bf * 4096;
    const u16* pB = sB + bf * 4096;
    s16x8 af[4], bfr[4];
    #pragma unroll
    for (int i = 0; i < 4; ++i)
      af[i] = *(const s16x8*)&pA[(wy*64 + i*16 + l4) * 32 + quad*8];
    #pragma unroll
    for (int j = 0; j < 4; ++j)
      bfr[j] = *(const s16x8*)&pB[(wx*64 + j*16 + l4) * 32 + quad*8];
    #pragma unroll
    for (int i = 0; i < 4; ++i)
      #pragma unroll
      for (int j = 0; j < 4; ++j)
        acc[i][j] = __builtin_amdgcn_mfma_f32_16x16x32_bf16(af[i], bfr[j], acc[i][j], 0, 0, 0);
  }

  // block-uniform region select (boundaries 1024/2048/3072 are 128-aligned)
  #pragma unroll
  for (int i = 0; i < 4; ++i) {
    const size_t row0 = mBase + wy*64 + i*16 + quad*4;
    #pragma unroll
    for (int j = 0; j < 4; ++j) {
      const int col = (int)nBase + wx*64 + j*16 + l4;
      if (nBase < 1024) {               // Q: fold (1/sqrt(64))*log2(e)
        #pragma unroll
        for (int rg = 0; rg < 4; ++rg)
          qkb[(row0 + rg) * 2048 + col] = f2bf(acc[i][j][rg] * 0.18033688011f);
      } else if (nBase < 2048) {        // K
        #pragma unroll
        for (int rg = 0; rg < 4; ++rg)
          qkb[(row0 + rg) * 2048 + col] = f2bf(acc[i][j][rg]);
      } else if (nBase < 3072) {        // V: transposed, 4 tokens packed
        const int cv = col - 2048, hh = cv >> 6, dd = cv & 63;
        const int bb = (int)(row0 >> 11), t0 = (int)(row0 & 2047);
        ushort4 pk;
        pk.x = f2bf(acc[i][j][0]); pk.y = f2bf(acc[i][j][1]);
        pk.z = f2bf(acc[i][j][2]); pk.w = f2bf(acc[i][j][3]);
        *(ushort4*)(vtg + ((size_t)((bb*16 + hh)*64 + dd)) * 2048 + t0) = pk;
      } else {                          // FFN1: silu -> A_cat cols 1024..5119
        #pragma unroll
        for (int rg = 0; rg < 4; ++rg) {
          float v = acc[i][j][rg];
          v = v / (1.0f + __expf(-v));
          acat[(row0 + rg) * (size_t)KC + 1024 + (col - 3072)] = f2bf(v);
        }
      }
    }
  }
}

// ---- final GEMM: d_out = x + A_cat[4096][5120] * B_cat[1024][5120]^T ----
// 256 threads = 4 waves (2x2), tile 64(M)x128(N), BK=32 double-buffered (24 KB).
// grid (8,64) = 512 blocks = 2 blocks/CU: cross-block overlap hides the
// vmcnt(0)+barrier drain (m97/m114 mechanism) that 1-block/CU R7/R8 couldn't.
__global__ __launch_bounds__(256, 2) void gemm_final(const u16* __restrict__ A,
                                                     const u16* __restrict__ Bt,
                                                     const float* __restrict__ x,
                                                     float* __restrict__ out) {
  __shared__ u16 sA[2 * 64 * 32];    // 8 KB
  __shared__ u16 sB[2 * 128 * 32];   // 16 KB
  const int t = threadIdx.x;
  const int lane = t & 63, wave = t >> 6;
  const int quad = lane >> 4, l4 = lane & 15;
  const int wy = wave >> 1, wx = wave & 1;   // 2x2 wave grid; wave tile 32(M)x64(N)
  const size_t mBase = (size_t)blockIdx.y * 64;
  const size_t nBase = (size_t)blockIdx.x * 128;
  const int r  = t >> 2;          // 0..63
  const int c8 = (t & 3) * 8;
  const u16* Ag  = A  + (mBase + r) * KC + c8;
  const u16* Bg0 = Bt + (nBase + r) * KC + c8;
  const u16* Bg1 = Bg0 + (size_t)64 * KC;
  char* sAb = (char*)sA + (wave << 10);
  char* sBb = (char*)sB + (wave << 10);

  f32x4 acc[2][4];
  #pragma unroll
  for (int i = 0; i < 2; ++i)
    #pragma unroll
    for (int j = 0; j < 4; ++j)
      acc[i][j] = (f32x4)0.0f;

  auto issue = [&](int bf, int k0) {
    gl2lds16(Ag  + k0, sAb + bf*4096);
    gl2lds16(Bg0 + k0, sBb + bf*8192);
    gl2lds16(Bg1 + k0, sBb + bf*8192 + 4096);
  };

  issue(0, 0);
  const int NIT = KC / 32;   // 160
  for (int kt = 0; kt < NIT; ++kt) {
    const int bf = kt & 1;
    __syncthreads();                        // drains buf[bf] (in flight since kt-1)
    if (kt + 1 < NIT) issue(bf ^ 1, (kt + 1) * 32);
    const u16* pA = sA + bf * 2048;   // u16 elements: 64*32
    const u16* pB = sB + bf * 4096;   // 128*32
    s16x8 af[2], bfr[4];
    #pragma unroll
    for (int i = 0; i < 2; ++i)
      af[i] = *(const s16x8*)&pA[(wy*32 + i*16 + l4) * 32 + quad*8];
    #pragma unroll
    for (int j = 0; j < 4; ++j)
      bfr[j] = *(const s16x8*)&pB[(wx*64 + j*16 + l4) * 32 + quad*8];
    #pragma unroll
    for (int i = 0; i < 2; ++i)
      #pragma unroll
      for (int j = 0; j < 4; ++j)
        acc[i][j] = __builtin_amdgcn_mfma_f32_16x16x32_bf16(af[i], bfr[j], acc[i][j], 0, 0, 0);
  }

  #pragma unroll
  for (int i = 0; i < 2; ++i) {
    const size_t row0 = mBase + wy*32 + i*16 + quad*4;
    #pragma unroll
    for (int j = 0; j < 4; ++j) {
      const int col = (int)nBase + wx*64 + j*16 + l4;
      #pragma unroll
      for (int rg = 0; rg < 4; ++rg) {
        const size_t idx = (row0 + rg) * (size_t)DM + col;
        out[idx] = x[idx] + acc[i][j][rg];
      }
    }
  }
}

// ------- causal flash attention, fixed-max, in-block split-K=2 over waves -------
// writes bf16 into A_cat cols 0..1023 (pitch 5120)
__global__ __launch_bounds__(128) void attn_k(const u16* __restrict__ qk,
                                              const u16* __restrict__ vtg,
                                              u16* __restrict__ acat) {
  const int bh = blockIdx.x, b = bh >> 4, h = bh & 15;
  const int qt = 63 - blockIdx.y;
  const int qw = qt * 32;
  const int wave = threadIdx.x >> 6, lane = threadIdx.x & 63;
  const int quad = lane >> 4, l4 = lane & 15;
  const u16* Qp = qk + (size_t)b * TT * 2048 + h * HD;
  const u16* Kp = Qp + 1024;
  const u16* Vp = vtg + (size_t)bh * 64 * 2048;

  __shared__ u16 Pb[2][32][72];
  __shared__ float Ob[32][68];
  __shared__ float Lb[32];

  s16x8 qf[2][2];
  #pragma unroll
  for (int mi = 0; mi < 2; ++mi)
    #pragma unroll
    for (int kf = 0; kf < 2; ++kf)
      qf[mi][kf] = *(const s16x8*)(Qp + (size_t)(qw + mi*16 + l4) * 2048 + kf*32 + quad*8);

  const s16x8 ones = {0x3F80,0x3F80,0x3F80,0x3F80,0x3F80,0x3F80,0x3F80,0x3F80};

  f32x4 o[2][4];
  f32x4 lacc[2];
  #pragma unroll
  for (int mi = 0; mi < 2; ++mi) {
    lacc[mi] = (f32x4)0.0f;
    #pragma unroll
    for (int ni = 0; ni < 4; ++ni) o[mi][ni] = (f32x4)0.0f;
  }

  const int n   = (qt + 2) >> 1;
  const int n0  = (n + 1) >> 1;
  const int kt0 = wave ? n0 : 0;
  const int kt1 = wave ? n : n0;

  for (int kt = kt0; kt < kt1; ++kt) {
    const int k0 = kt * 64;

    f32x4 st[4][2];
    #pragma unroll
    for (int nj = 0; nj < 4; ++nj) {
      const u16* kr = Kp + (size_t)(k0 + nj*16 + l4) * 2048 + quad*8;
      const s16x8 kf0 = *(const s16x8*)kr;
      const s16x8 kf1 = *(const s16x8*)(kr + 32);
      #pragma unroll
      for (int mi = 0; mi < 2; ++mi) {
        f32x4 a = (f32x4)0.0f;
        a = __builtin_amdgcn_mfma_f32_16x16x32_bf16(kf0, qf[mi][0], a, 0, 0, 0);
        a = __builtin_amdgcn_mfma_f32_16x16x32_bf16(kf1, qf[mi][1], a, 0, 0, 0);
        st[nj][mi] = a;
      }
    }

    s16x8 vb[2][4];
    #pragma unroll
    for (int kf2 = 0; kf2 < 2; ++kf2)
      #pragma unroll
      for (int ni = 0; ni < 4; ++ni)
        vb[kf2][ni] = *(const s16x8*)(Vp + (size_t)(ni*16 + l4) * 2048 + k0 + kf2*32 + quad*8);

    if (k0 + 63 > qw) {
      #pragma unroll
      for (int nj = 0; nj < 4; ++nj)
        #pragma unroll
        for (int mi = 0; mi < 2; ++mi)
          #pragma unroll
          for (int rg = 0; rg < 4; ++rg) {
            const int key = k0 + nj*16 + quad*4 + rg;
            const int q   = qw + mi*16 + l4;
            if (key > q) st[nj][mi][rg] = -1e30f;
          }
    }

    #pragma unroll
    for (int nj = 0; nj < 4; ++nj)
      #pragma unroll
      for (int mi = 0; mi < 2; ++mi) {
        float p0 = __builtin_amdgcn_exp2f(st[nj][mi][0]);
        float p1 = __builtin_amdgcn_exp2f(st[nj][mi][1]);
        float p2 = __builtin_amdgcn_exp2f(st[nj][mi][2]);
        float p3 = __builtin_amdgcn_exp2f(st[nj][mi][3]);
        uint2 w;
        w.x = __builtin_amdgcn_perm(__builtin_bit_cast(u32, p1),
                                    __builtin_bit_cast(u32, p0), 0x07060302u);
        w.y = __builtin_amdgcn_perm(__builtin_bit_cast(u32, p3),
                                    __builtin_bit_cast(u32, p2), 0x07060302u);
        *(uint2*)&Pb[wave][mi*16 + l4][nj*16 + quad*4] = w;
      }

    #pragma unroll
    for (int kf2 = 0; kf2 < 2; ++kf2) {
      s16x8 pa[2];
      #pragma unroll
      for (int mi = 0; mi < 2; ++mi)
        pa[mi] = *(const s16x8*)&Pb[wave][mi*16 + l4][kf2*32 + quad*8];
      #pragma unroll
      for (int mi = 0; mi < 2; ++mi) {
        lacc[mi] = __builtin_amdgcn_mfma_f32_16x16x32_bf16(pa[mi], ones, lacc[mi], 0, 0, 0);
        #pragma unroll
        for (int ni = 0; ni < 4; ++ni)
          o[mi][ni] = __builtin_amdgcn_mfma_f32_16x16x32_bf16(pa[mi], vb[kf2][ni], o[mi][ni], 0, 0, 0);
      }
    }
  }

  if (wave == 1) {
    #pragma unroll
    for (int mi = 0; mi < 2; ++mi)
      #pragma unroll
      for (int rg = 0; rg < 4; ++rg) {
        const int row = mi*16 + quad*4 + rg;
        #pragma unroll
        for (int ni = 0; ni < 4; ++ni) Ob[row][ni*16 + l4] = o[mi][ni][rg];
        if (l4 == 0) Lb[row] = lacc[mi][rg];
      }
  }
  __syncthreads();
  if (wave == 0) {
    #pragma unroll
    for (int mi = 0; mi < 2; ++mi)
      #pragma unroll
      for (int rg = 0; rg < 4; ++rg) {
        const int row = mi*16 + quad*4 + rg;
        const float inv = 1.0f / (lacc[mi][rg] + Lb[row]);
        #pragma unroll
        for (int ni = 0; ni < 4; ++ni)
          Pb[0][row][ni*16 + l4] = f2bf((o[mi][ni][rg] + Ob[row][ni*16 + l4]) * inv);
      }
    #pragma unroll
    for (int it = 0; it < 4; ++it) {
      const int row = it*8 + (lane >> 3);
      const int c0  = (lane & 7) * 8;
      const s16x8 pk = *(const s16x8*)&Pb[0][row][c0];
      *(s16x8*)(acat + ((size_t)b * TT + qw + row) * KC + h*HD + c0) = pk;
    }
  }
}

extern "C" void kernel_launch(void* const* d_in, const int* in_sizes, int n_in,
                              void* d_out, int out_size, void* d_ws, size_t ws_size,
                              hipStream_t stream) {
  (void)in_sizes; (void)n_in; (void)out_size; (void)ws_size;
  const float* x  = (const float*)d_in[0];
  const float* nw = (const float*)d_in[1];
  const float* Wq = (const float*)d_in[2];
  const float* Wk = (const float*)d_in[3];
  const float* Wv = (const float*)d_in[4];
  const float* Wo = (const float*)d_in[5];
  const float* W1 = (const float*)d_in[6];
  const float* W2 = (const float*)d_in[7];

  char* ws = (char*)d_ws;
  u16*   xn      = (u16*)(ws);                          //  8 MB  [4096][1024]
  u16*   wqkv1_t = (u16*)(ws + ((size_t)8  << 20));     // 14 MB  [7168][1024] Wq|Wk|Wv|W1 ^T
  u16*   bcat    = (u16*)(ws + ((size_t)22 << 20));     // 10 MB  [1024][5120] Wo^T|W2^T
  u16*   qkb     = (u16*)(ws + ((size_t)32 << 20));     // 16 MB  [4096][2048] (q|k)
  u16*   vtg     = (u16*)(ws + ((size_t)48 << 20));     //  8 MB  [32][64][2048] V^T
  u16*   acat    = (u16*)(ws + ((size_t)56 << 20));     // 40 MB  [4096][5120] attn_o|ff1
  float* dout    = (float*)d_out;                       // 16 MB  [4096][1024] fp32

  rmsnorm_k<<<BT, 256, 0, stream>>>(x, nw, xn);
  const dim3 tb(32, 8);
  wtrans_k<<<dim3(32, 32),  tb, 0, stream>>>(Wq, wqkv1_t,                      1024, 1024, 1024, 0);
  wtrans_k<<<dim3(32, 32),  tb, 0, stream>>>(Wk, wqkv1_t + (size_t)1024*1024,  1024, 1024, 1024, 0);
  wtrans_k<<<dim3(32, 32),  tb, 0, stream>>>(Wv, wqkv1_t + (size_t)2048*1024,  1024, 1024, 1024, 0);
  wtrans_k<<<dim3(128, 32), tb, 0, stream>>>(W1, wqkv1_t + (size_t)3072*1024,  1024, 4096, 1024, 0);
  wtrans_k<<<dim3(32, 32),  tb, 0, stream>>>(Wo, bcat,                         1024, 1024, 5120, 0);
  wtrans_k<<<dim3(32, 128), tb, 0, stream>>>(W2, bcat,                         4096, 1024, 5120, 1024);

  gemm_fused<<<dim3(56, 32), 256, 0, stream>>>(xn, wqkv1_t, qkb, vtg, acat);
  attn_k<<<dim3(32, 64), 128, 0, stream>>>(qkb, vtg, acat);
  gemm_final<<<dim3(8, 64), 256, 0, stream>>>(acat, bcat, x, dout);
}